// Round 3
// baseline (6589.201 us; speedup 1.0000x reference)
//
#include <hip/hip_runtime.h>
#include <hip/hip_bf16.h>

#define B_    128
#define T_    64
#define E_    300
#define HID_  1024
#define G4_   4096
#define C_    512
#define NA_   196
#define KATT_ 512
#define MIMG_ 25088

typedef short s16x8 __attribute__((ext_vector_type(8)));
typedef float f32x4 __attribute__((ext_vector_type(4)));

__device__ __forceinline__ unsigned short f2bf(float f) {
  __hip_bfloat16 h = __float2bfloat16(f);
  return __builtin_bit_cast(unsigned short, h);
}
__device__ __forceinline__ float bf2f(unsigned short u) {
  __hip_bfloat16 h = __builtin_bit_cast(__hip_bfloat16, u);
  return __bfloat162float(h);
}

// ---------------------------------------------------------------------------
__global__ __launch_bounds__(256) void conv_bf16(const float* __restrict__ in,
                                                 unsigned short* __restrict__ out,
                                                 int n) {
  int i = blockIdx.x * 256 + threadIdx.x;
  if (i < n) out[i] = f2bf(in[i]);
}

__global__ __launch_bounds__(256) void conv_pad320(const float* __restrict__ in,
                                                   unsigned short* __restrict__ out,
                                                   int rows) {
  int i = blockIdx.x * 256 + threadIdx.x;
  if (i >= rows * 320) return;
  int r = i / 320, k = i - r * 320;
  out[i] = (k < 300) ? f2bf(in[(size_t)r * 300 + k]) : (unsigned short)0;
}

__global__ __launch_bounds__(256) void gather_emb(const int* __restrict__ desc,
                                                  const float* __restrict__ emb,
                                                  unsigned short* __restrict__ out) {
  int i = blockIdx.x * 256 + threadIdx.x;   // 8192*320
  int m = i / 320, k = i - m * 320;
  float v = (k < 300) ? emb[(size_t)desc[m] * 300 + k] : 0.f;
  out[i] = f2bf(v);
}

// ---------------------------------------------------------------------------
// bf16 MFMA GEMM, 128x128 tile, BK=32, 4 waves each 64x64.
// C = A[M,K] @ Bw[N,K]^T (+bias +bias2).
// mode 0: Cf fp32 row-major; mode 1: Cb bf16 row-major;
// mode 2: Cb bf16 Xg-blocked [m>>7][col][m&127];
// mode 3: fused attention score: sc[row] += sum_col tanh(v + tu[b][col])*wp[col]
// ---------------------------------------------------------------------------
__global__ __launch_bounds__(256) void gemm_mfma(
    const unsigned short* __restrict__ A, int lda,
    const unsigned short* __restrict__ Bw, int Kd,
    const float* __restrict__ bias, const float* __restrict__ bias2,
    float* __restrict__ Cf, unsigned short* __restrict__ Cb, int ldc,
    int mode, const float* __restrict__ tu, const float* __restrict__ wp,
    float* __restrict__ sc)
{
  __shared__ unsigned short As[128 * 40];
  __shared__ unsigned short Bs[128 * 40];
  const int tid = threadIdx.x;
  const int m0 = blockIdx.y << 7, n0 = blockIdx.x << 7;
  const int w = tid >> 6, l = tid & 63;
  const int wr = w >> 1, wc = w & 1;
  const int lrow = l & 15, lk = (l >> 4) << 3;
  const int srow = tid >> 2, schunk = (tid & 3) << 3;

  f32x4 acc[4][4];
#pragma unroll
  for (int i = 0; i < 4; i++)
#pragma unroll
    for (int j = 0; j < 4; j++) acc[i][j] = (f32x4){0.f, 0.f, 0.f, 0.f};

  const unsigned short* Ap = A + (size_t)(m0 + srow) * lda + schunk;
  const unsigned short* Bp = Bw + (size_t)(n0 + srow) * Kd + schunk;
  const size_t arep = (size_t)64 * lda, brep = (size_t)64 * Kd;

  for (int k0 = 0; k0 < Kd; k0 += 32) {
    *(uint4*)&As[srow * 40 + schunk]        = *(const uint4*)(Ap + k0);
    *(uint4*)&As[(srow + 64) * 40 + schunk] = *(const uint4*)(Ap + arep + k0);
    *(uint4*)&Bs[srow * 40 + schunk]        = *(const uint4*)(Bp + k0);
    *(uint4*)&Bs[(srow + 64) * 40 + schunk] = *(const uint4*)(Bp + brep + k0);
    __syncthreads();
    s16x8 af[4], bfr[4];
#pragma unroll
    for (int i = 0; i < 4; i++) {
      af[i]  = *(const s16x8*)&As[(wr * 64 + i * 16 + lrow) * 40 + lk];
      bfr[i] = *(const s16x8*)&Bs[(wc * 64 + i * 16 + lrow) * 40 + lk];
    }
#pragma unroll
    for (int i = 0; i < 4; i++)
#pragma unroll
      for (int j = 0; j < 4; j++)
        acc[i][j] = __builtin_amdgcn_mfma_f32_16x16x32_bf16(af[i], bfr[j], acc[i][j], 0, 0, 0);
    __syncthreads();
  }

  const int quad = l >> 4;
  if (mode == 3) {
    // fused score epilogue: per row partial = sum over this block's 128 cols
#pragma unroll
    for (int i = 0; i < 4; i++) {
#pragma unroll
      for (int r = 0; r < 4; r++) {
        int row = m0 + wr * 64 + i * 16 + quad * 4 + r;
        int b = row / NA_;
        float partial = 0.f;
#pragma unroll
        for (int j = 0; j < 4; j++) {
          int col = n0 + wc * 64 + j * 16 + lrow;
          float v = acc[i][j][r] + tu[(size_t)b * KATT_ + col];
          partial += tanhf(v) * wp[col];
        }
        partial += __shfl_xor(partial, 1);
        partial += __shfl_xor(partial, 2);
        partial += __shfl_xor(partial, 4);
        partial += __shfl_xor(partial, 8);
        if (lrow == 0) unsafeAtomicAdd(&sc[row], partial);
      }
    }
    return;
  }

#pragma unroll
  for (int i = 0; i < 4; i++) {
    int rbase = m0 + wr * 64 + i * 16 + quad * 4;
#pragma unroll
    for (int j = 0; j < 4; j++) {
      int col = n0 + wc * 64 + j * 16 + lrow;
      float badd = (bias ? bias[col] : 0.f) + (bias2 ? bias2[col] : 0.f);
#pragma unroll
      for (int r = 0; r < 4; r++) {
        float v = acc[i][j][r] + badd;
        int m = rbase + r;
        if (mode == 0)      Cf[(size_t)m * ldc + col] = v;
        else if (mode == 1) Cb[(size_t)m * ldc + col] = f2bf(v);
        else {  // mode 2: Xg blocked [t][col][b]
          size_t off = ((size_t)(m >> 7)) * 524288 + (size_t)col * 128 + (m & 127);
          Cb[off] = f2bf(v);
        }
      }
    }
  }
}

// ---------------------------------------------------------------------------
// Persistent LSTM: one launch, 64 steps, grid-wide barrier per step.
// 256 blocks = (2 batch-halves) x (128 j-blocks of 8 cols). W_hh slice
// (4 gates x 8 cols = 32 rows x 1024) lives in LDS (xor-swizzled, 64 KB).
// Wave (mt,nt): m-tile mt (16 batch rows), n-tile nt (16 of 32 gate-cols).
// Gate-col order r = jj*4+g so the 4 gates of (b,jj) sit in 4 adjacent lanes
// -> gate exchange via 3 shfl_xor, no LDS. c-state in registers.
// ---------------------------------------------------------------------------
__global__ __launch_bounds__(512, 1) void lstm_persist(
    const unsigned short* __restrict__ Xg,     // [64][4096][128] blocked
    const unsigned short* __restrict__ Whh,    // [4096][1024]
    unsigned short* __restrict__ h0b,          // [128][1024] (zeroed)
    unsigned short* __restrict__ h1b,
    float* __restrict__ u,                     // [128][1024] fp32 final h
    unsigned short* __restrict__ ub,           // [128][1024] bf16 final h
    unsigned int* __restrict__ cnt)            // barrier counter (zeroed)
{
  __shared__ unsigned short Bs[32 * 1024];     // exactly 64 KB
  const int tid = threadIdx.x;
  const int w = tid >> 6, l = tid & 63;
  const int mb = blockIdx.x & 1, jb = blockIdx.x >> 1;   // jb 0..127
  const int mt = w & 3, nt = w >> 2;
  const int quad = l >> 4, nl = l & 15;
  const int g = l & 3, jjl = (l >> 2) & 3;

  // one-time: W_hh slice -> LDS, rows r = jj*4+g, chunk xor-swizzle (r&7)
  for (int i = tid; i < 4096; i += 512) {
    int r = i >> 7, ch = i & 127;
    int wrow = (r & 3) * 1024 + jb * 8 + (r >> 2);
    uint4 v = *(const uint4*)(Whh + (size_t)wrow * 1024 + ch * 8);
    *(uint4*)&Bs[r * 1024 + (ch ^ (r & 7)) * 8] = v;
  }
  __syncthreads();

  const int brow_a = mb * 64 + mt * 16 + nl;    // A-fragment row (batch)
  const int bq = mb * 64 + mt * 16 + quad * 4;  // c/h batch-row base
  const int j = jb * 8 + nt * 4 + jjl;          // hidden col 0..1023
  const int col = (g << 10) + j;                // Xg gate-col 0..4095
  const int nrow = nt * 16 + nl;                // LDS row 0..31

  float cr[4] = {0.f, 0.f, 0.f, 0.f};

  for (int step = 0; step < 64; step++) {
    const unsigned short* hin = (step & 1) ? h1b : h0b;
    unsigned short* hout = (step & 1) ? h0b : h1b;

    const unsigned short* Ap = hin + (size_t)brow_a * 1024;
    f32x4 acc0 = {0.f,0.f,0.f,0.f}, acc1 = {0.f,0.f,0.f,0.f};
#pragma unroll 8
    for (int kc = 0; kc < 32; kc++) {
      s16x8 a = *(const s16x8*)(Ap + (kc << 5) + (quad << 3));
      int slot = ((kc << 2) | quad) ^ (nrow & 7);
      s16x8 b = *(const s16x8*)&Bs[nrow * 1024 + (slot << 3)];
      if (kc & 1) acc1 = __builtin_amdgcn_mfma_f32_16x16x32_bf16(a, b, acc1, 0, 0, 0);
      else        acc0 = __builtin_amdgcn_mfma_f32_16x16x32_bf16(a, b, acc0, 0, 0, 0);
    }
    f32x4 acc = acc0 + acc1;

    ushort4 xg4 = *(const ushort4*)(Xg + (size_t)step * 524288 + (size_t)col * 128 + bq);
    float hn[4];
#pragma unroll
    for (int r = 0; r < 4; r++) {
      unsigned short xr = (r == 0) ? xg4.x : (r == 1) ? xg4.y : (r == 2) ? xg4.z : xg4.w;
      float v = acc[r] + bf2f(xr);          // full preactivation of gate g
      float x1 = __shfl_xor(v, 1);          // gate g^1
      float x2 = __shfl_xor(v, 2);          // gate g^2
      float x3 = __shfl_xor(x1, 2);         // gate g^3
      float gi = (g == 0) ? v  : (g == 1) ? x1 : (g == 2) ? x2 : x3;
      float gf = (g == 0) ? x1 : (g == 1) ? v  : (g == 2) ? x3 : x2;
      float gg = (g == 0) ? x2 : (g == 1) ? x3 : (g == 2) ? v  : x1;
      float go = (g == 0) ? x3 : (g == 1) ? x2 : (g == 2) ? x1 : v;
      float si = 1.f / (1.f + expf(-gi));
      float sf = 1.f / (1.f + expf(-gf));
      float so = 1.f / (1.f + expf(-go));
      float cn = sf * cr[r] + si * tanhf(gg);
      cr[r] = cn;
      hn[r] = so * tanhf(cn);
    }
    if (g == 0) {
      if (step == 63) {
#pragma unroll
        for (int r = 0; r < 4; r++) {
          size_t idx = (size_t)(bq + r) * 1024 + j;
          u[idx] = hn[r];
          ub[idx] = f2bf(hn[r]);
        }
      } else {
#pragma unroll
        for (int r = 0; r < 4; r++)
          hout[(size_t)(bq + r) * 1024 + j] = f2bf(hn[r]);
      }
    }
    if (step < 63) {
      __threadfence();
      __syncthreads();
      if (tid == 0) {
        __hip_atomic_fetch_add(cnt, 1u, __ATOMIC_RELAXED, __HIP_MEMORY_SCOPE_AGENT);
        unsigned int target = 256u * (unsigned)(step + 1);
        while (__hip_atomic_load(cnt, __ATOMIC_RELAXED, __HIP_MEMORY_SCOPE_AGENT) < target)
          __builtin_amdgcn_s_sleep(2);
      }
      __syncthreads();
      __threadfence();
    }
  }
}

// ---------------------------------------------------------------------------
// t_u = ub @ Wq^T + bq : M=128, N=512, K=1024. 32 blocks x 512 thr, MFMA.
// ---------------------------------------------------------------------------
__global__ __launch_bounds__(512) void tu_gemm(
    const unsigned short* __restrict__ ub, const unsigned short* __restrict__ Wq,
    const float* __restrict__ bq, float* __restrict__ tu)
{
  __shared__ unsigned short Bs[16 * 1032];
  const int tid = threadIdx.x;
  const int w = tid >> 6, l = tid & 63;
  const int n0 = blockIdx.x << 4;
  const int quad = l >> 4, nl = l & 15;
  for (int i = tid; i < 2048; i += 512) {
    int r = i >> 7, ch = i & 127;
    *(uint4*)&Bs[r * 1032 + ch * 8] = *(const uint4*)(Wq + (size_t)(n0 + r) * 1024 + ch * 8);
  }
  __syncthreads();
  const unsigned short* Ap = ub + (size_t)(w * 16 + nl) * 1024;
  f32x4 acc0 = {0.f,0.f,0.f,0.f}, acc1 = {0.f,0.f,0.f,0.f};
#pragma unroll 8
  for (int kc = 0; kc < 32; kc++) {
    s16x8 a = *(const s16x8*)(Ap + (kc << 5) + (quad << 3));
    s16x8 b = *(const s16x8*)&Bs[nl * 1032 + (kc << 5) + (quad << 3)];
    if (kc & 1) acc1 = __builtin_amdgcn_mfma_f32_16x16x32_bf16(a, b, acc1, 0, 0, 0);
    else        acc0 = __builtin_amdgcn_mfma_f32_16x16x32_bf16(a, b, acc0, 0, 0, 0);
  }
  f32x4 acc = acc0 + acc1;
  int colg = n0 + nl;
  float badd = bq[colg];
#pragma unroll
  for (int r = 0; r < 4; r++)
    tu[(size_t)(w * 16 + quad * 4 + r) * KATT_ + colg] = acc[r] + badd;
}

// ---------------------------------------------------------------------------
// per-(b,hgroup): softmax over 196 (redundant per hg) + pooled v; u += v.
// ---------------------------------------------------------------------------
__global__ __launch_bounds__(256) void softmax_pool2(
    const float* __restrict__ sc, const unsigned short* __restrict__ outimg,
    float* __restrict__ u)
{
  int hg = blockIdx.x, b = blockIdx.y, tid = threadIdx.x;
  __shared__ float p[NA_];
  __shared__ float red[8];
  float v = (tid < NA_) ? sc[b * NA_ + tid] : -1e30f;
  float m = v;
#pragma unroll
  for (int off = 32; off; off >>= 1) m = fmaxf(m, __shfl_down(m, off, 64));
  if ((tid & 63) == 0) red[tid >> 6] = m;
  __syncthreads();
  float bm = fmaxf(fmaxf(red[0], red[1]), fmaxf(red[2], red[3]));
  float e = (tid < NA_) ? expf(v - bm) : 0.f;
  float s = e;
#pragma unroll
  for (int off = 32; off; off >>= 1) s += __shfl_down(s, off, 64);
  if ((tid & 63) == 0) red[4 + (tid >> 6)] = s;
  __syncthreads();
  float bs = red[4] + red[5] + red[6] + red[7];
  if (tid < NA_) p[tid] = e / bs;
  __syncthreads();
  int h = hg * 128 + (tid >> 1);
  int half = tid & 1;
  const unsigned short* r = outimg + (size_t)b * (HID_ * NA_) + (size_t)h * NA_ + half * 98;
  float acc = 0.f;
#pragma unroll 7
  for (int n = 0; n < 98; n += 2) {
    unsigned int pk = *(const unsigned int*)(r + n);
    acc += bf2f((unsigned short)(pk & 0xffff)) * p[half * 98 + n];
    acc += bf2f((unsigned short)(pk >> 16))    * p[half * 98 + n + 1];
  }
  acc += __shfl_xor(acc, 1);
  if (half == 0) u[(size_t)b * HID_ + h] += acc;
}

// ---------------------------------------------------------------------------
extern "C" void kernel_launch(void* const* d_in, const int* in_sizes, int n_in,
                              void* d_out, int out_size, void* d_ws, size_t ws_size,
                              hipStream_t stream) {
  const int*   desc   = (const int*)  d_in[0];
  const float* img    = (const float*)d_in[1];
  const float* emb    = (const float*)d_in[2];
  const float* W_ih   = (const float*)d_in[3];
  const float* W_hh   = (const float*)d_in[4];
  const float* b_ih   = (const float*)d_in[5];
  const float* b_hh   = (const float*)d_in[6];
  const float* W_img  = (const float*)d_in[7];
  const float* b_img  = (const float*)d_in[8];
  const float* Wl_img = (const float*)d_in[9];
  const float* Wl_q   = (const float*)d_in[10];
  const float* bl_q   = (const float*)d_in[11];
  const float* wl_p   = (const float*)d_in[12];
  float* u = (float*)d_out;

  uint8_t* base = (uint8_t*)d_ws;
  unsigned short* Xgb    = (unsigned short*)(base);              // 67,108,864 B
  unsigned short* imgb   = (unsigned short*)(base);              // alias (after LSTM)
  unsigned short* outimg = (unsigned short*)(base + 67108864);   // 51,380,224
  unsigned short* Whhb   = (unsigned short*)(base + 118489088);  //  8,388,608
  unsigned short* Wihb   = (unsigned short*)(base + 126877696);  //  2,621,440
  unsigned short* Aemb   = (unsigned short*)(base + 129499136);  //  5,242,880
  unsigned short* Wimgb  = (unsigned short*)(base + 134742016);  //  1,048,576
  unsigned short* Wlimgb = (unsigned short*)(base + 135790592);  //  2,097,152
  unsigned short* Wlqb   = (unsigned short*)(base + 137887744);  //  2,097,152
  unsigned short* ubb    = (unsigned short*)(base + 139984896);  //    262,144
  unsigned short* h0b    = (unsigned short*)(base + 140247040);  //    262,144
  unsigned short* h1b    = (unsigned short*)(base + 140509184);  //    262,144
  float*          tub    = (float*)(base + 140771328);           //    262,144
  float*          scb0   = (float*)(base + 141033472);           //    100,352
  float*          scb1   = (float*)(base + 141133824);           //    100,352 (contig w/ scb0)
  unsigned int*   cnt    = (unsigned int*)(base + 141234176);    //        256

  // ---- bf16 conversions ----
  conv_bf16<<<(G4_ * HID_ + 255) / 256, 256, 0, stream>>>(W_hh, Whhb, G4_ * HID_);
  conv_pad320<<<(G4_ * 320 + 255) / 256, 256, 0, stream>>>(W_ih, Wihb, G4_);
  gather_emb<<<(8192 * 320) / 256, 256, 0, stream>>>(desc, emb, Aemb);
  conv_bf16<<<(HID_ * C_ + 255) / 256, 256, 0, stream>>>(W_img, Wimgb, HID_ * C_);
  conv_bf16<<<(2 * KATT_ * HID_ + 255) / 256, 256, 0, stream>>>(Wl_img, Wlimgb, 2 * KATT_ * HID_);
  conv_bf16<<<(2 * KATT_ * HID_ + 255) / 256, 256, 0, stream>>>(Wl_q, Wlqb, 2 * KATT_ * HID_);

  hipMemsetAsync(h0b, 0, 262144, stream);
  hipMemsetAsync(cnt, 0, 256, stream);
  hipMemsetAsync(scb0, 0, 200704, stream);   // scb0 + scb1

  // Xg = emb[desc] @ W_ih^T + b_ih + b_hh -> blocked bf16 [64][4096][128]
  gemm_mfma<<<dim3(32, 64), 256, 0, stream>>>(Aemb, 320, Wihb, 320, b_ih, b_hh,
                                              nullptr, Xgb, 0, 2, nullptr, nullptr, nullptr);

  // ---- LSTM: single persistent launch, 64 steps ----
  lstm_persist<<<256, 512, 0, stream>>>(Xgb, Whhb, h0b, h1b, u, ubb, cnt);

  // img -> bf16 (aliases dead Xg region), then out_img GEMM
  conv_bf16<<<(MIMG_ * C_ + 255) / 256, 256, 0, stream>>>(img, imgb, MIMG_ * C_);
  gemm_mfma<<<dim3(8, 196), 256, 0, stream>>>(imgb, C_, Wimgb, C_, b_img, nullptr,
                                              nullptr, outimg, HID_, 1, nullptr, nullptr, nullptr);

  for (int i = 0; i < 2; i++) {
    float* scb = (i == 0) ? scb0 : scb1;
    if (i == 1)  // refresh bf16 copy of u after layer-0 update
      conv_bf16<<<512, 256, 0, stream>>>(u, ubb, B_ * HID_);
    tu_gemm<<<32, 512, 0, stream>>>(ubb, Wlqb + (size_t)i * KATT_ * HID_,
                                    bl_q + i * KATT_, tub);
    // fused: scores += sum tanh(out_img@Wl_img^T + t_u) * wl_p  (no t_img materialized)
    gemm_mfma<<<dim3(4, 196), 256, 0, stream>>>(outimg, HID_,
                                                Wlimgb + (size_t)i * KATT_ * HID_, HID_,
                                                nullptr, nullptr, nullptr, nullptr, 0, 3,
                                                tub, wl_p + i * KATT_, scb);
    softmax_pool2<<<dim3(8, B_), 256, 0, stream>>>(scb, outimg, u);
  }
}

// Round 4
// 1348.776 us; speedup vs baseline: 4.8853x; 4.8853x over previous
//
#include <hip/hip_runtime.h>
#include <hip/hip_bf16.h>

#define B_    128
#define T_    64
#define E_    300
#define HID_  1024
#define G4_   4096
#define C_    512
#define NA_   196
#define KATT_ 512
#define MIMG_ 25088

typedef short s16x8 __attribute__((ext_vector_type(8)));
typedef float f32x4 __attribute__((ext_vector_type(4)));

__device__ __forceinline__ unsigned short f2bf(float f) {
  __hip_bfloat16 h = __float2bfloat16(f);
  return __builtin_bit_cast(unsigned short, h);
}
__device__ __forceinline__ float bf2f(unsigned short u) {
  __hip_bfloat16 h = __builtin_bit_cast(__hip_bfloat16, u);
  return __bfloat162float(h);
}

// ---------------------------------------------------------------------------
__global__ __launch_bounds__(256) void conv_bf16(const float* __restrict__ in,
                                                 unsigned short* __restrict__ out,
                                                 int n) {
  int i = blockIdx.x * 256 + threadIdx.x;
  if (i < n) out[i] = f2bf(in[i]);
}

__global__ __launch_bounds__(256) void conv_pad320(const float* __restrict__ in,
                                                   unsigned short* __restrict__ out,
                                                   int rows) {
  int i = blockIdx.x * 256 + threadIdx.x;
  if (i >= rows * 320) return;
  int r = i / 320, k = i - r * 320;
  out[i] = (k < 300) ? f2bf(in[(size_t)r * 300 + k]) : (unsigned short)0;
}

__global__ __launch_bounds__(256) void gather_emb(const int* __restrict__ desc,
                                                  const float* __restrict__ emb,
                                                  unsigned short* __restrict__ out) {
  int i = blockIdx.x * 256 + threadIdx.x;   // 8192*320
  int m = i / 320, k = i - m * 320;
  float v = (k < 300) ? emb[(size_t)desc[m] * 300 + k] : 0.f;
  out[i] = f2bf(v);
}

// ---------------------------------------------------------------------------
// bf16 MFMA GEMM, 128x128 tile, BK=32, 4 waves each 64x64.
// C = A[M,K] @ Bw[N,K]^T (+bias +bias2).
// mode 0: Cf fp32 row-major; mode 1: Cb bf16 row-major;
// mode 2: Cb bf16 Xg-blocked [m>>7][col][m&127];
// mode 3: fused attention score: sc[row] += sum_col tanh(v + tu[b][col])*wp[col]
// ---------------------------------------------------------------------------
__global__ __launch_bounds__(256) void gemm_mfma(
    const unsigned short* __restrict__ A, int lda,
    const unsigned short* __restrict__ Bw, int Kd,
    const float* __restrict__ bias, const float* __restrict__ bias2,
    float* __restrict__ Cf, unsigned short* __restrict__ Cb, int ldc,
    int mode, const float* __restrict__ tu, const float* __restrict__ wp,
    float* __restrict__ sc)
{
  __shared__ unsigned short As[128 * 40];
  __shared__ unsigned short Bs[128 * 40];
  const int tid = threadIdx.x;
  const int m0 = blockIdx.y << 7, n0 = blockIdx.x << 7;
  const int w = tid >> 6, l = tid & 63;
  const int wr = w >> 1, wc = w & 1;
  const int lrow = l & 15, lk = (l >> 4) << 3;
  const int srow = tid >> 2, schunk = (tid & 3) << 3;

  f32x4 acc[4][4];
#pragma unroll
  for (int i = 0; i < 4; i++)
#pragma unroll
    for (int j = 0; j < 4; j++) acc[i][j] = (f32x4){0.f, 0.f, 0.f, 0.f};

  const unsigned short* Ap = A + (size_t)(m0 + srow) * lda + schunk;
  const unsigned short* Bp = Bw + (size_t)(n0 + srow) * Kd + schunk;
  const size_t arep = (size_t)64 * lda, brep = (size_t)64 * Kd;

  for (int k0 = 0; k0 < Kd; k0 += 32) {
    *(uint4*)&As[srow * 40 + schunk]        = *(const uint4*)(Ap + k0);
    *(uint4*)&As[(srow + 64) * 40 + schunk] = *(const uint4*)(Ap + arep + k0);
    *(uint4*)&Bs[srow * 40 + schunk]        = *(const uint4*)(Bp + k0);
    *(uint4*)&Bs[(srow + 64) * 40 + schunk] = *(const uint4*)(Bp + brep + k0);
    __syncthreads();
    s16x8 af[4], bfr[4];
#pragma unroll
    for (int i = 0; i < 4; i++) {
      af[i]  = *(const s16x8*)&As[(wr * 64 + i * 16 + lrow) * 40 + lk];
      bfr[i] = *(const s16x8*)&Bs[(wc * 64 + i * 16 + lrow) * 40 + lk];
    }
#pragma unroll
    for (int i = 0; i < 4; i++)
#pragma unroll
      for (int j = 0; j < 4; j++)
        acc[i][j] = __builtin_amdgcn_mfma_f32_16x16x32_bf16(af[i], bfr[j], acc[i][j], 0, 0, 0);
    __syncthreads();
  }

  const int quad = l >> 4;
  if (mode == 3) {
#pragma unroll
    for (int i = 0; i < 4; i++) {
#pragma unroll
      for (int r = 0; r < 4; r++) {
        int row = m0 + wr * 64 + i * 16 + quad * 4 + r;
        int b = row / NA_;
        float partial = 0.f;
#pragma unroll
        for (int j = 0; j < 4; j++) {
          int col = n0 + wc * 64 + j * 16 + lrow;
          float v = acc[i][j][r] + tu[(size_t)b * KATT_ + col];
          partial += tanhf(v) * wp[col];
        }
        partial += __shfl_xor(partial, 1);
        partial += __shfl_xor(partial, 2);
        partial += __shfl_xor(partial, 4);
        partial += __shfl_xor(partial, 8);
        if (lrow == 0) unsafeAtomicAdd(&sc[row], partial);
      }
    }
    return;
  }

#pragma unroll
  for (int i = 0; i < 4; i++) {
    int rbase = m0 + wr * 64 + i * 16 + quad * 4;
#pragma unroll
    for (int j = 0; j < 4; j++) {
      int col = n0 + wc * 64 + j * 16 + lrow;
      float badd = (bias ? bias[col] : 0.f) + (bias2 ? bias2[col] : 0.f);
#pragma unroll
      for (int r = 0; r < 4; r++) {
        float v = acc[i][j][r] + badd;
        int m = rbase + r;
        if (mode == 0)      Cf[(size_t)m * ldc + col] = v;
        else if (mode == 1) Cb[(size_t)m * ldc + col] = f2bf(v);
        else {  // mode 2: Xg blocked [t][col][b]
          size_t off = ((size_t)(m >> 7)) * 524288 + (size_t)col * 128 + (m & 127);
          Cb[off] = f2bf(v);
        }
      }
    }
  }
}

// ---------------------------------------------------------------------------
// Per-step LSTM kernel (launched 64x). Grid 256 = (mb batch-half) x (jb 8-col
// block). 512 thr = 8 waves = (mt 4 m-tiles) x (nt 2 n-tiles). W_hh slice
// (32 rows = 8 cols x 4 gates, interleaved r=jj*4+g) staged to LDS each step
// (xor-swizzled, conflict-free b128 reads). Gate mixing via 3 shfl_xor.
// c-state in transposed global [j][b] fp32 (float4, broadcast across g-lanes).
// ---------------------------------------------------------------------------
__global__ __launch_bounds__(512) void lstm_step2(
    const unsigned short* __restrict__ hin,    // [128][1024] bf16
    const unsigned short* __restrict__ Xg_t,   // [4096][128] bf16 (this step)
    const unsigned short* __restrict__ Whh,    // [4096][1024] bf16
    float* __restrict__ cbuf,                  // [1024][128] fp32 (zeroed)
    unsigned short* __restrict__ hout,         // [128][1024] bf16
    float* __restrict__ u,                     // null, or [128][1024] fp32
    unsigned short* __restrict__ ub)           // null, or bf16 copy of u
{
  __shared__ unsigned short Bs[32 * 1024];     // 64 KB
  const int tid = threadIdx.x;
  const int w = tid >> 6, l = tid & 63;
  const int mb = blockIdx.x & 1, jb = blockIdx.x >> 1;   // jb 0..127
  const int mt = w & 3, nt = w >> 2;
  const int quad = l >> 4, nl = l & 15;
  const int g = l & 3, jjl = (l >> 2) & 3;

  const int brow_a = mb * 64 + mt * 16 + nl;    // A-fragment row (batch)
  const int bq = mb * 64 + mt * 16 + quad * 4;  // c/h batch-row base
  const int j = jb * 8 + nt * 4 + jjl;          // hidden col 0..1023
  const int col = (g << 10) + j;                // Xg gate-col 0..4095
  const int nrow = nt * 16 + nl;                // LDS row 0..31

  // early independent loads (hide behind LDS staging)
  ushort4 xg4 = *(const ushort4*)(Xg_t + (size_t)col * 128 + bq);
  float4 c4 = *(const float4*)(cbuf + (size_t)j * 128 + bq);

  // stage W_hh slice -> LDS, rows r = jj*4+g, chunk xor-swizzle (r&7)
  for (int i = tid; i < 4096; i += 512) {
    int r = i >> 7, ch = i & 127;
    int wrow = (r & 3) * 1024 + jb * 8 + (r >> 2);
    uint4 v = *(const uint4*)(Whh + (size_t)wrow * 1024 + ch * 8);
    *(uint4*)&Bs[r * 1024 + (ch ^ (r & 7)) * 8] = v;
  }
  __syncthreads();

  const unsigned short* Ap = hin + (size_t)brow_a * 1024;
  f32x4 acc0 = {0.f,0.f,0.f,0.f}, acc1 = {0.f,0.f,0.f,0.f};
#pragma unroll
  for (int kc = 0; kc < 32; kc++) {
    s16x8 a = *(const s16x8*)(Ap + (kc << 5) + (quad << 3));
    int slot = ((kc << 2) | quad) ^ (nrow & 7);
    s16x8 b = *(const s16x8*)&Bs[nrow * 1024 + (slot << 3)];
    if (kc & 1) acc1 = __builtin_amdgcn_mfma_f32_16x16x32_bf16(a, b, acc1, 0, 0, 0);
    else        acc0 = __builtin_amdgcn_mfma_f32_16x16x32_bf16(a, b, acc0, 0, 0, 0);
  }
  f32x4 acc = acc0 + acc1;

  float cn4[4], hn4[4];
#pragma unroll
  for (int r = 0; r < 4; r++) {
    unsigned short xr = (r == 0) ? xg4.x : (r == 1) ? xg4.y : (r == 2) ? xg4.z : xg4.w;
    float v = acc[r] + bf2f(xr);          // full preactivation of gate g
    float x1 = __shfl_xor(v, 1);
    float x2 = __shfl_xor(v, 2);
    float x3 = __shfl_xor(x1, 2);
    float gi = (g == 0) ? v  : (g == 1) ? x1 : (g == 2) ? x2 : x3;
    float gf = (g == 0) ? x1 : (g == 1) ? v  : (g == 2) ? x3 : x2;
    float gg = (g == 0) ? x2 : (g == 1) ? x3 : (g == 2) ? v  : x1;
    float go = (g == 0) ? x3 : (g == 1) ? x2 : (g == 2) ? x1 : v;
    float si = 1.f / (1.f + expf(-gi));
    float sf = 1.f / (1.f + expf(-gf));
    float so = 1.f / (1.f + expf(-go));
    float cprev = (r == 0) ? c4.x : (r == 1) ? c4.y : (r == 2) ? c4.z : c4.w;
    float cn = sf * cprev + si * tanhf(gg);
    cn4[r] = cn;
    hn4[r] = so * tanhf(cn);
  }
  if (g == 0) {
    float4 co = {cn4[0], cn4[1], cn4[2], cn4[3]};
    *(float4*)(cbuf + (size_t)j * 128 + bq) = co;
#pragma unroll
    for (int r = 0; r < 4; r++)
      hout[(size_t)(bq + r) * 1024 + j] = f2bf(hn4[r]);
    if (u) {
#pragma unroll
      for (int r = 0; r < 4; r++) {
        size_t idx = (size_t)(bq + r) * 1024 + j;
        u[idx] = hn4[r];
        ub[idx] = f2bf(hn4[r]);
      }
    }
  }
}

// ---------------------------------------------------------------------------
// t_u = ub @ Wq^T + bq : M=128, N=512, K=1024. 32 blocks x 512 thr, MFMA.
// ---------------------------------------------------------------------------
__global__ __launch_bounds__(512) void tu_gemm(
    const unsigned short* __restrict__ ub, const unsigned short* __restrict__ Wq,
    const float* __restrict__ bq, float* __restrict__ tu)
{
  __shared__ unsigned short Bs[16 * 1032];
  const int tid = threadIdx.x;
  const int w = tid >> 6, l = tid & 63;
  const int n0 = blockIdx.x << 4;
  const int quad = l >> 4, nl = l & 15;
  for (int i = tid; i < 2048; i += 512) {
    int r = i >> 7, ch = i & 127;
    *(uint4*)&Bs[r * 1032 + ch * 8] = *(const uint4*)(Wq + (size_t)(n0 + r) * 1024 + ch * 8);
  }
  __syncthreads();
  const unsigned short* Ap = ub + (size_t)(w * 16 + nl) * 1024;
  f32x4 acc0 = {0.f,0.f,0.f,0.f}, acc1 = {0.f,0.f,0.f,0.f};
#pragma unroll 8
  for (int kc = 0; kc < 32; kc++) {
    s16x8 a = *(const s16x8*)(Ap + (kc << 5) + (quad << 3));
    s16x8 b = *(const s16x8*)&Bs[nl * 1032 + (kc << 5) + (quad << 3)];
    if (kc & 1) acc1 = __builtin_amdgcn_mfma_f32_16x16x32_bf16(a, b, acc1, 0, 0, 0);
    else        acc0 = __builtin_amdgcn_mfma_f32_16x16x32_bf16(a, b, acc0, 0, 0, 0);
  }
  f32x4 acc = acc0 + acc1;
  int colg = n0 + nl;
  float badd = bq[colg];
#pragma unroll
  for (int r = 0; r < 4; r++)
    tu[(size_t)(w * 16 + quad * 4 + r) * KATT_ + colg] = acc[r] + badd;
}

// ---------------------------------------------------------------------------
// per-(b,hgroup): softmax over 196 (redundant per hg) + pooled v; u += v.
// ---------------------------------------------------------------------------
__global__ __launch_bounds__(256) void softmax_pool2(
    const float* __restrict__ sc, const unsigned short* __restrict__ outimg,
    float* __restrict__ u)
{
  int hg = blockIdx.x, b = blockIdx.y, tid = threadIdx.x;
  __shared__ float p[NA_];
  __shared__ float red[8];
  float v = (tid < NA_) ? sc[b * NA_ + tid] : -1e30f;
  float m = v;
#pragma unroll
  for (int off = 32; off; off >>= 1) m = fmaxf(m, __shfl_down(m, off, 64));
  if ((tid & 63) == 0) red[tid >> 6] = m;
  __syncthreads();
  float bm = fmaxf(fmaxf(red[0], red[1]), fmaxf(red[2], red[3]));
  float e = (tid < NA_) ? expf(v - bm) : 0.f;
  float s = e;
#pragma unroll
  for (int off = 32; off; off >>= 1) s += __shfl_down(s, off, 64);
  if ((tid & 63) == 0) red[4 + (tid >> 6)] = s;
  __syncthreads();
  float bs = red[4] + red[5] + red[6] + red[7];
  if (tid < NA_) p[tid] = e / bs;
  __syncthreads();
  int h = hg * 128 + (tid >> 1);
  int half = tid & 1;
  const unsigned short* r = outimg + (size_t)b * (HID_ * NA_) + (size_t)h * NA_ + half * 98;
  float acc = 0.f;
#pragma unroll 7
  for (int n = 0; n < 98; n += 2) {
    unsigned int pk = *(const unsigned int*)(r + n);
    acc += bf2f((unsigned short)(pk & 0xffff)) * p[half * 98 + n];
    acc += bf2f((unsigned short)(pk >> 16))    * p[half * 98 + n + 1];
  }
  acc += __shfl_xor(acc, 1);
  if (half == 0) u[(size_t)b * HID_ + h] += acc;
}

// ---------------------------------------------------------------------------
extern "C" void kernel_launch(void* const* d_in, const int* in_sizes, int n_in,
                              void* d_out, int out_size, void* d_ws, size_t ws_size,
                              hipStream_t stream) {
  const int*   desc   = (const int*)  d_in[0];
  const float* img    = (const float*)d_in[1];
  const float* emb    = (const float*)d_in[2];
  const float* W_ih   = (const float*)d_in[3];
  const float* W_hh   = (const float*)d_in[4];
  const float* b_ih   = (const float*)d_in[5];
  const float* b_hh   = (const float*)d_in[6];
  const float* W_img  = (const float*)d_in[7];
  const float* b_img  = (const float*)d_in[8];
  const float* Wl_img = (const float*)d_in[9];
  const float* Wl_q   = (const float*)d_in[10];
  const float* bl_q   = (const float*)d_in[11];
  const float* wl_p   = (const float*)d_in[12];
  float* u = (float*)d_out;

  uint8_t* base = (uint8_t*)d_ws;
  unsigned short* Xgb    = (unsigned short*)(base);              // 67,108,864 B
  unsigned short* imgb   = (unsigned short*)(base);              // alias (after LSTM)
  unsigned short* outimg = (unsigned short*)(base + 67108864);   // 51,380,224
  unsigned short* Whhb   = (unsigned short*)(base + 118489088);  //  8,388,608
  unsigned short* Wihb   = (unsigned short*)(base + 126877696);  //  2,621,440
  unsigned short* Aemb   = (unsigned short*)(base + 129499136);  //  5,242,880
  unsigned short* Wimgb  = (unsigned short*)(base + 134742016);  //  1,048,576
  unsigned short* Wlimgb = (unsigned short*)(base + 135790592);  //  2,097,152
  unsigned short* Wlqb   = (unsigned short*)(base + 137887744);  //  2,097,152
  unsigned short* ubb    = (unsigned short*)(base + 139984896);  //    262,144
  unsigned short* h0b    = (unsigned short*)(base + 140247040);  //    262,144
  unsigned short* h1b    = (unsigned short*)(base + 140509184);  //    262,144
  float*          tub    = (float*)(base + 140771328);           //    262,144
  float*          scb0   = (float*)(base + 141033472);           //    100,352
  float*          scb1   = (float*)(base + 141133824);           //    100,352
  float*          cbuf   = (float*)(base + 141234176);           //    524,288

  // ---- bf16 conversions ----
  conv_bf16<<<(G4_ * HID_ + 255) / 256, 256, 0, stream>>>(W_hh, Whhb, G4_ * HID_);
  conv_pad320<<<(G4_ * 320 + 255) / 256, 256, 0, stream>>>(W_ih, Wihb, G4_);
  gather_emb<<<(8192 * 320) / 256, 256, 0, stream>>>(desc, emb, Aemb);
  conv_bf16<<<(HID_ * C_ + 255) / 256, 256, 0, stream>>>(W_img, Wimgb, HID_ * C_);
  conv_bf16<<<(2 * KATT_ * HID_ + 255) / 256, 256, 0, stream>>>(Wl_img, Wlimgb, 2 * KATT_ * HID_);
  conv_bf16<<<(2 * KATT_ * HID_ + 255) / 256, 256, 0, stream>>>(Wl_q, Wlqb, 2 * KATT_ * HID_);

  hipMemsetAsync(h0b, 0, 262144, stream);
  hipMemsetAsync(cbuf, 0, 524288, stream);
  hipMemsetAsync(scb0, 0, 200704, stream);   // scb0 + scb1 (contiguous)

  // Xg = emb[desc] @ W_ih^T + b_ih + b_hh -> blocked bf16 [64][4096][128]
  gemm_mfma<<<dim3(32, 64), 256, 0, stream>>>(Aemb, 320, Wihb, 320, b_ih, b_hh,
                                              nullptr, Xgb, 0, 2, nullptr, nullptr, nullptr);

  // ---- LSTM: 64 per-step launches (no grid sync) ----
  for (int t = 0; t < T_; t++) {
    const unsigned short* hi = (t & 1) ? h1b : h0b;
    unsigned short* ho = (t & 1) ? h0b : h1b;
    lstm_step2<<<256, 512, 0, stream>>>(hi, Xgb + (size_t)t * 524288, Whhb, cbuf, ho,
                                        (t == T_ - 1) ? u : nullptr,
                                        (t == T_ - 1) ? ubb : nullptr);
  }

  // img -> bf16 (aliases dead Xg region), then out_img GEMM
  conv_bf16<<<(MIMG_ * C_ + 255) / 256, 256, 0, stream>>>(img, imgb, MIMG_ * C_);
  gemm_mfma<<<dim3(8, 196), 256, 0, stream>>>(imgb, C_, Wimgb, C_, b_img, nullptr,
                                              nullptr, outimg, HID_, 1, nullptr, nullptr, nullptr);

  for (int i = 0; i < 2; i++) {
    float* scb = (i == 0) ? scb0 : scb1;
    if (i == 1)  // refresh bf16 copy of u after layer-0 update
      conv_bf16<<<512, 256, 0, stream>>>(u, ubb, B_ * HID_);
    tu_gemm<<<32, 512, 0, stream>>>(ubb, Wlqb + (size_t)i * KATT_ * HID_,
                                    bl_q + i * KATT_, tub);
    // fused: scores += sum tanh(out_img@Wl_img^T + t_u) * wl_p
    gemm_mfma<<<dim3(4, 196), 256, 0, stream>>>(outimg, HID_,
                                                Wlimgb + (size_t)i * KATT_ * HID_, HID_,
                                                nullptr, nullptr, nullptr, nullptr, 0, 3,
                                                tub, wl_p + i * KATT_, scb);
    softmax_pool2<<<dim3(8, B_), 256, 0, stream>>>(scb, outimg, u);
  }
}